// Round 11
// baseline (731.120 us; speedup 1.0000x reference)
//
#include <hip/hip_runtime.h>

typedef __bf16 bf16x8 __attribute__((ext_vector_type(8)));
typedef float f32x4 __attribute__((ext_vector_type(4)));

__device__ inline unsigned short f2b(float f) {
  unsigned int u = __float_as_uint(f);
  u += 0x7fffu + ((u >> 16) & 1u);
  return (unsigned short)(u >> 16);
}
__device__ inline float b2f(unsigned short u) {
  return __uint_as_float(((unsigned int)u) << 16);
}

// XOR swizzle for [R][128] bf16 LDS tiles (element index)
__device__ inline int swz(int r, int c) { return r * 128 + (c ^ ((r & 7) << 3)); }

__device__ inline bf16x8 ldfrag(const unsigned short* p) {
  uint4 v = *(const uint4*)p;
  bf16x8 r;
  __builtin_memcpy(&r, &v, 16);
  return r;
}

// ------------- weight prep: fp32 [K][N] -> bf16 hi/lo [n][k], 11 slots 128x128 ----
__global__ __launch_bounds__(256) void prep_wt(
    const float* __restrict__ W_in, const float* __restrict__ W_lin,
    const float* __restrict__ W1, const float* __restrict__ W2,
    const float* __restrict__ W_out, unsigned short* __restrict__ Wh,
    unsigned short* __restrict__ Wl)
{
  int slot = blockIdx.y;
  int e = blockIdx.x * 256 + threadIdx.x;   // 0..16383
  int n = e >> 7, k = e & 127;
  const float* srcp; int N;
  if (slot == 0)      { srcp = W_in;                   N = 128; }
  else if (slot < 4)  { srcp = W_lin + (slot-1)*16384; N = 128; }
  else if (slot < 7)  { srcp = W1   + (slot-4)*16384;  N = 128; }
  else if (slot < 10) { srcp = W2   + (slot-7)*16384;  N = 128; }
  else                { srcp = W_out;                  N = 40;  }
  float v = (n < N) ? srcp[k * N + n] : 0.f;
  unsigned short hi = f2b(v);
  float lo = v - b2f(hi);
  Wh[slot * 16384 + e] = hi;
  Wl[slot * 16384 + e] = f2b(lo);
}

// ------------- plain GEMM: C = act(A[Mx128] @ W[128xNcols] + b), A fp32 ----------
// 3-term bf16 split emulation: A*W = Ah*Wh + Ah*Wl + Al*Wh  (error ~2^-17)
// BM=32 tiles (MF=1): 2x the blocks of BM=64 -> occupancy hides L2 weight-load
// latency (R10 profile: 20% occupancy, 6.5% MfmaUtil, latency-bound).
template<int WM, int WN, int MF, int NF, bool RELU>
__global__ __launch_bounds__(256) void gemm_k(
    const float* __restrict__ Ap, const unsigned short* __restrict__ Wh,
    const unsigned short* __restrict__ Wl, const float* __restrict__ bias,
    float* __restrict__ Cp, int M, int Ncols)
{
  constexpr int BM = WM * MF * 16;
  static_assert(BM * 128 % 1024 == 0, "");
  __shared__ __align__(16) unsigned short ldsAh[BM * 128];
  __shared__ __align__(16) unsigned short ldsAl[BM * 128];

  const int tid = threadIdx.x;
  const int row0 = blockIdx.x * BM;

  constexpr int AIT = BM * 128 / 1024;
#pragma unroll
  for (int it = 0; it < AIT; ++it) {
    int flat = it * 1024 + tid * 4;
    int r = flat >> 7, c = flat & 127;
    int gr = row0 + r;
    float4 v = make_float4(0.f, 0.f, 0.f, 0.f);
    if (gr < M) v = *(const float4*)(Ap + (size_t)gr * 128 + c);
    ushort4 h4, l4;
    h4.x = f2b(v.x); l4.x = f2b(v.x - b2f(h4.x));
    h4.y = f2b(v.y); l4.y = f2b(v.y - b2f(h4.y));
    h4.z = f2b(v.z); l4.z = f2b(v.z - b2f(h4.z));
    h4.w = f2b(v.w); l4.w = f2b(v.w - b2f(h4.w));
    *(ushort4*)&ldsAh[swz(r, c)] = h4;
    *(ushort4*)&ldsAl[swz(r, c)] = l4;
  }
  __syncthreads();

  const int wid = tid >> 6, lane = tid & 63;
  const int wm = wid / WN, wn = wid % WN;
  const int l15 = lane & 15, lk = lane >> 4;

  f32x4 acc[MF][NF];
#pragma unroll
  for (int mi = 0; mi < MF; ++mi)
#pragma unroll
    for (int ni = 0; ni < NF; ++ni)
      acc[mi][ni] = (f32x4){0.f, 0.f, 0.f, 0.f};

  const unsigned short* wbh = Wh + (size_t)(wn * NF * 16 + l15) * 128;
  const unsigned short* wbl = Wl + (size_t)(wn * NF * 16 + l15) * 128;

#pragma unroll
  for (int kk = 0; kk < 4; ++kk) {
    const int kc = kk * 32 + lk * 8;
    bf16x8 ah[MF], al[MF];
#pragma unroll
    for (int mi = 0; mi < MF; ++mi) {
      int rr = wm * MF * 16 + mi * 16 + l15;
      ah[mi] = ldfrag(&ldsAh[swz(rr, kc)]);
      al[mi] = ldfrag(&ldsAl[swz(rr, kc)]);
    }
    bf16x8 bh[NF], bl[NF];
#pragma unroll
    for (int ni = 0; ni < NF; ++ni) {
      bh[ni] = ldfrag(wbh + ni * 16 * 128 + kc);
      bl[ni] = ldfrag(wbl + ni * 16 * 128 + kc);
    }
#pragma unroll
    for (int mi = 0; mi < MF; ++mi)
#pragma unroll
      for (int ni = 0; ni < NF; ++ni) {
        acc[mi][ni] = __builtin_amdgcn_mfma_f32_16x16x32_bf16(ah[mi], bl[ni], acc[mi][ni], 0, 0, 0);
        acc[mi][ni] = __builtin_amdgcn_mfma_f32_16x16x32_bf16(al[mi], bh[ni], acc[mi][ni], 0, 0, 0);
        acc[mi][ni] = __builtin_amdgcn_mfma_f32_16x16x32_bf16(ah[mi], bh[ni], acc[mi][ni], 0, 0, 0);
      }
  }

#pragma unroll
  for (int ni = 0; ni < NF; ++ni) {
    int col = wn * NF * 16 + ni * 16 + l15;
    if (col >= Ncols) continue;
    float bc = bias[col];
#pragma unroll
    for (int mi = 0; mi < MF; ++mi) {
      int rbase = row0 + wm * MF * 16 + mi * 16 + lk * 4;
#pragma unroll
      for (int j = 0; j < 4; ++j) {
        int r = rbase + j;
        if (r >= M) continue;
        float v = acc[mi][ni][j] + bc;
        if (RELU) v = fmaxf(v, 0.f);
        Cp[(size_t)r * Ncols + col] = v;
      }
    }
  }
}

// ------------- fused double GEMM: h = (relu(((1+eps)h2+neigh)@W1+b1)) @ W2 + b2 --
// BM=32 (MF=1). Phase1 acc -> t -> hi/lo bf16 into (dead) staging LDS -> Phase2.
__global__ __launch_bounds__(256) void fusedgemm_k(
    const float* __restrict__ h2, const float* __restrict__ neigh,
    const float* __restrict__ epsp,
    const unsigned short* __restrict__ Wh1, const unsigned short* __restrict__ Wl1,
    const float* __restrict__ b1,
    const unsigned short* __restrict__ Wh2, const unsigned short* __restrict__ Wl2,
    const float* __restrict__ b2, float* __restrict__ Hout, int M)
{
  constexpr int WM = 2, WN = 2, MF = 1, NF = 4;
  constexpr int BM = WM * MF * 16;   // 32
  __shared__ __align__(16) unsigned short ldsAh[BM * 128];
  __shared__ __align__(16) unsigned short ldsAl[BM * 128];

  const int tid = threadIdx.x;
  const int row0 = blockIdx.x * BM;
  const float epsf = 1.0f + epsp[0];

  // stage A = (1+eps)*h2 + neigh  (fp32 -> hi/lo, swizzled)
#pragma unroll
  for (int it = 0; it < BM * 128 / 1024; ++it) {
    int flat = it * 1024 + tid * 4;
    int r = flat >> 7, c = flat & 127;
    int gr = row0 + r;
    float4 v = make_float4(0.f, 0.f, 0.f, 0.f);
    if (gr < M) {
      v = *(const float4*)(h2 + (size_t)gr * 128 + c);
      float4 ng = *(const float4*)(neigh + (size_t)gr * 128 + c);
      v = make_float4(fmaf(epsf, v.x, ng.x), fmaf(epsf, v.y, ng.y),
                      fmaf(epsf, v.z, ng.z), fmaf(epsf, v.w, ng.w));
    }
    ushort4 h4, l4;
    h4.x = f2b(v.x); l4.x = f2b(v.x - b2f(h4.x));
    h4.y = f2b(v.y); l4.y = f2b(v.y - b2f(h4.y));
    h4.z = f2b(v.z); l4.z = f2b(v.z - b2f(h4.z));
    h4.w = f2b(v.w); l4.w = f2b(v.w - b2f(h4.w));
    *(ushort4*)&ldsAh[swz(r, c)] = h4;
    *(ushort4*)&ldsAl[swz(r, c)] = l4;
  }
  __syncthreads();

  const int wid = tid >> 6, lane = tid & 63;
  const int wm = wid / WN, wn = wid % WN;
  const int l15 = lane & 15, lk = lane >> 4;

  f32x4 acc[NF];
#pragma unroll
  for (int ni = 0; ni < NF; ++ni)
    acc[ni] = (f32x4){0.f, 0.f, 0.f, 0.f};

  // ---- phase 1: t = A @ W1 ----
  {
    const unsigned short* wbh = Wh1 + (size_t)(wn * NF * 16 + l15) * 128;
    const unsigned short* wbl = Wl1 + (size_t)(wn * NF * 16 + l15) * 128;
#pragma unroll
    for (int kk = 0; kk < 4; ++kk) {
      const int kc = kk * 32 + lk * 8;
      int rr = wm * 16 + l15;
      bf16x8 ah = ldfrag(&ldsAh[swz(rr, kc)]);
      bf16x8 al = ldfrag(&ldsAl[swz(rr, kc)]);
      bf16x8 bh[NF], bl[NF];
#pragma unroll
      for (int ni = 0; ni < NF; ++ni) {
        bh[ni] = ldfrag(wbh + ni * 16 * 128 + kc);
        bl[ni] = ldfrag(wbl + ni * 16 * 128 + kc);
      }
#pragma unroll
      for (int ni = 0; ni < NF; ++ni) {
        acc[ni] = __builtin_amdgcn_mfma_f32_16x16x32_bf16(ah, bl[ni], acc[ni], 0, 0, 0);
        acc[ni] = __builtin_amdgcn_mfma_f32_16x16x32_bf16(al, bh[ni], acc[ni], 0, 0, 0);
        acc[ni] = __builtin_amdgcn_mfma_f32_16x16x32_bf16(ah, bh[ni], acc[ni], 0, 0, 0);
      }
    }
  }
  __syncthreads();   // all phase-1 LDS reads done before t overwrites staging

  // t = relu(acc + b1) -> hi/lo bf16 into staging LDS (block-local rows/cols)
#pragma unroll
  for (int ni = 0; ni < NF; ++ni) {
    int c = wn * NF * 16 + ni * 16 + l15;
    float bc = b1[c];
#pragma unroll
    for (int j = 0; j < 4; ++j) {
      int r = wm * 16 + lk * 4 + j;
      float v = fmaxf(acc[ni][j] + bc, 0.f);
      unsigned short hi = f2b(v);
      ldsAh[swz(r, c)] = hi;
      ldsAl[swz(r, c)] = f2b(v - b2f(hi));
      acc[ni][j] = 0.f;   // reset for phase 2
    }
  }
  __syncthreads();   // t complete before phase-2 reads

  // ---- phase 2: h = t @ W2 ----
  {
    const unsigned short* wbh = Wh2 + (size_t)(wn * NF * 16 + l15) * 128;
    const unsigned short* wbl = Wl2 + (size_t)(wn * NF * 16 + l15) * 128;
#pragma unroll
    for (int kk = 0; kk < 4; ++kk) {
      const int kc = kk * 32 + lk * 8;
      int rr = wm * 16 + l15;
      bf16x8 ah = ldfrag(&ldsAh[swz(rr, kc)]);
      bf16x8 al = ldfrag(&ldsAl[swz(rr, kc)]);
      bf16x8 bh[NF], bl[NF];
#pragma unroll
      for (int ni = 0; ni < NF; ++ni) {
        bh[ni] = ldfrag(wbh + ni * 16 * 128 + kc);
        bl[ni] = ldfrag(wbl + ni * 16 * 128 + kc);
      }
#pragma unroll
      for (int ni = 0; ni < NF; ++ni) {
        acc[ni] = __builtin_amdgcn_mfma_f32_16x16x32_bf16(ah, bl[ni], acc[ni], 0, 0, 0);
        acc[ni] = __builtin_amdgcn_mfma_f32_16x16x32_bf16(al, bh[ni], acc[ni], 0, 0, 0);
        acc[ni] = __builtin_amdgcn_mfma_f32_16x16x32_bf16(ah, bh[ni], acc[ni], 0, 0, 0);
      }
    }
  }

#pragma unroll
  for (int ni = 0; ni < NF; ++ni) {
    int col = wn * NF * 16 + ni * 16 + l15;
    float bc = b2[col];
#pragma unroll
    for (int j = 0; j < 4; ++j) {
      int r = row0 + wm * 16 + lk * 4 + j;
      if (r >= M) continue;
      Hout[(size_t)r * 128 + col] = acc[ni][j] + bc;
    }
  }
}

// ------------- maxk: exact fp32 top-32 select; write packed bf16 dense rows ------
__global__ __launch_bounds__(256) void maxk_k(const float* __restrict__ h,
                                              unsigned int* __restrict__ hs, int M)
{
  int row = blockIdx.x * 4 + (threadIdx.x >> 6);
  if (row >= M) return;
  int lane = threadIdx.x & 63;
  float2 pr = *(const float2*)(h + (size_t)row * 128 + lane * 2);
  auto key = [](float f) -> unsigned int {
    unsigned int b = __float_as_uint(f);
    return (b & 0x80000000u) ? ~b : (b | 0x80000000u);
  };
  unsigned int k0 = key(pr.x), k1 = key(pr.y);
  unsigned int thr = 0;
#pragma unroll
  for (int b = 31; b >= 0; --b) {
    unsigned int t = thr | (1u << b);
    int c = __popcll(__ballot(k0 >= t)) + __popcll(__ballot(k1 >= t));
    if (c >= 32) thr = t;   // uniform across wave
  }
  unsigned long long g0 = __ballot(k0 > thr), g1 = __ballot(k1 > thr);
  unsigned long long e0 = __ballot(k0 == thr), e1 = __ballot(k1 == thr);
  int cgt = __popcll(g0) + __popcll(g1);
  unsigned long long mlt = (1ull << lane) - 1ull;
  unsigned long long mle = mlt | (1ull << lane);
  bool keep0 = (k0 > thr) ||
               ((k0 == thr) && (cgt + __popcll(e0 & mlt) + __popcll(e1 & mlt)) < 32);
  bool keep1 = (k1 > thr) ||
               ((k1 == thr) && (cgt + __popcll(e0 & mle) + __popcll(e1 & mlt)) < 32);
  unsigned int w0 = keep0 ? (unsigned int)f2b(pr.x) : 0u;
  unsigned int w1 = keep1 ? (unsigned int)f2b(pr.y) : 0u;
  hs[(size_t)row * 64 + lane] = w0 | (w1 << 16);
}

// ------------- CSR build (once per call; graph reused across 3 layers) -----------
__global__ __launch_bounds__(256) void hist_k(const int* __restrict__ dst,
                                              int* __restrict__ cnt, int E)
{
  int e = blockIdx.x * 256 + threadIdx.x;
  if (e < E) atomicAdd(&cnt[dst[e]], 1);
}

__global__ __launch_bounds__(256) void bsum_k(const int* __restrict__ cnt,
                                              int* __restrict__ bsum, int M)
{
  __shared__ int s[256];
  int i = blockIdx.x * 256 + threadIdx.x;
  int t = threadIdx.x;
  s[t] = (i < M) ? cnt[i] : 0;
  __syncthreads();
  for (int st = 128; st > 0; st >>= 1) {
    if (t < st) s[t] += s[t + st];
    __syncthreads();
  }
  if (t == 0) bsum[blockIdx.x] = s[0];
}

__global__ __launch_bounds__(1024) void scanb_k(int* __restrict__ bsum, int NB)
{
  __shared__ int s[1024];
  int t = threadIdx.x;
  int v = (t < NB) ? bsum[t] : 0;
  s[t] = v;
  __syncthreads();
  for (int st = 1; st < 1024; st <<= 1) {
    int a = (t >= st) ? s[t - st] : 0;
    __syncthreads();
    s[t] += a;
    __syncthreads();
  }
  if (t < NB) bsum[t] = s[t] - v;   // exclusive
}

__global__ __launch_bounds__(256) void scano_k(const int* __restrict__ cnt,
                                               const int* __restrict__ bsum,
                                               int* __restrict__ offs,
                                               int* __restrict__ cur, int M, int E)
{
  __shared__ int s[256];
  int i = blockIdx.x * 256 + threadIdx.x;
  int t = threadIdx.x;
  int v = (i < M) ? cnt[i] : 0;
  s[t] = v;
  __syncthreads();
  for (int st = 1; st < 256; st <<= 1) {
    int a = (t >= st) ? s[t - st] : 0;
    __syncthreads();
    s[t] += a;
    __syncthreads();
  }
  int excl = s[t] - v + bsum[blockIdx.x];
  if (i < M) { offs[i] = excl; cur[i] = excl; }
  if (blockIdx.x == 0 && t == 0) offs[M] = E;
}

__global__ __launch_bounds__(256) void fill_k(const int* __restrict__ src,
                                              const int* __restrict__ dst,
                                              int* __restrict__ cur,
                                              unsigned short* __restrict__ eidx, int E)
{
  int e = blockIdx.x * 256 + threadIdx.x;
  if (e >= E) return;
  int d = dst[e];
  int p = atomicAdd(&cur[d], 1);
  eidx[p] = (unsigned short)src[e];
}

// ------------- gather: neigh[d] = sum of bf16 hs rows over in-edges --------------
__global__ __launch_bounds__(256) void gather_k(
    const unsigned int* __restrict__ hs, const int* __restrict__ offs,
    const unsigned short* __restrict__ eidx, float* __restrict__ neigh, int M)
{
  const int w = threadIdx.x >> 6, lane = threadIdx.x & 63;
  const int d = blockIdx.x * 4 + w;
  if (d >= M) return;
  const int start = offs[d], end = offs[d + 1];
  float ax = 0.f, ay = 0.f;
  int i = start;
  for (; i + 4 <= end; i += 4) {
    int s0 = eidx[i], s1 = eidx[i + 1], s2 = eidx[i + 2], s3 = eidx[i + 3];
    unsigned int u0 = hs[(size_t)s0 * 64 + lane];
    unsigned int u1 = hs[(size_t)s1 * 64 + lane];
    unsigned int u2 = hs[(size_t)s2 * 64 + lane];
    unsigned int u3 = hs[(size_t)s3 * 64 + lane];
    ax += (b2f(u0 & 0xffffu) + b2f(u1 & 0xffffu)) +
          (b2f(u2 & 0xffffu) + b2f(u3 & 0xffffu));
    ay += (b2f(u0 >> 16) + b2f(u1 >> 16)) + (b2f(u2 >> 16) + b2f(u3 >> 16));
  }
  for (; i < end; ++i) {
    unsigned int u0 = hs[(size_t)eidx[i] * 64 + lane];
    ax += b2f(u0 & 0xffffu);
    ay += b2f(u0 >> 16);
  }
  float2 o;
  o.x = ax;
  o.y = ay;
  *(float2*)(neigh + (size_t)d * 128 + (size_t)lane * 2) = o;
}

extern "C" void kernel_launch(void* const* d_in, const int* in_sizes, int n_in,
                              void* d_out, int out_size, void* d_ws, size_t ws_size,
                              hipStream_t stream)
{
  const float* x     = (const float*)d_in[0];
  const int*   src   = (const int*)d_in[1];
  const int*   dst   = (const int*)d_in[2];
  const float* W_in  = (const float*)d_in[3];
  const float* b_in  = (const float*)d_in[4];
  const float* W_lin = (const float*)d_in[5];
  const float* b_lin = (const float*)d_in[6];
  const float* W1    = (const float*)d_in[7];
  const float* b1    = (const float*)d_in[8];
  const float* W2    = (const float*)d_in[9];
  const float* b2    = (const float*)d_in[10];
  const float* eps   = (const float*)d_in[11];
  const float* W_out = (const float*)d_in[12];
  const float* b_out = (const float*)d_in[13];

  const int M = in_sizes[0] / 128;   // 50000
  const int E = in_sizes[1];         // 800000

  const int NB = (M + 255) / 256;
  char* ws = (char*)d_ws;
  unsigned short* Wh = (unsigned short*)ws;
  size_t off = (size_t)11 * 16384 * 2;
  unsigned short* Wl = (unsigned short*)(ws + off); off += (size_t)11 * 16384 * 2;
  float* PA    = (float*)(ws + off); off += (size_t)M * 128 * 4;
  float* PB    = (float*)(ws + off); off += (size_t)M * 128 * 4;
  float* neigh = (float*)(ws + off); off += (size_t)M * 128 * 4;
  int* offs = (int*)(ws + off); off += (size_t)(M + 1) * 4;
  unsigned short* eidx = (unsigned short*)(ws + off); off += (size_t)E * 2;
  int* cnt  = (int*)(ws + off); off += (size_t)M * 4;
  int* cur  = (int*)(ws + off); off += (size_t)M * 4;
  int* bsum = (int*)(ws + off); off += (size_t)NB * 4;

  dim3 blk(256);
  prep_wt<<<dim3(64, 11), blk, 0, stream>>>(W_in, W_lin, W1, W2, W_out, Wh, Wl);

  // ---- CSR build (graph constant across layers) ----
  (void)hipMemsetAsync(cnt, 0, (size_t)M * 4, stream);
  hist_k<<<(E + 255) / 256, blk, 0, stream>>>(dst, cnt, E);
  bsum_k<<<NB, blk, 0, stream>>>(cnt, bsum, M);
  scanb_k<<<1, 1024, 0, stream>>>(bsum, NB);
  scano_k<<<NB, blk, 0, stream>>>(cnt, bsum, offs, cur, M, E);
  fill_k<<<(E + 255) / 256, blk, 0, stream>>>(src, dst, cur, eidx, E);

  const int gm32 = (M + 31) / 32;   // BM=32 tiles

  // h = relu(x @ W_in + b_in) -> PA   (h lives in PA for the whole net)
  float* hbuf = PA;
  float* h2buf = PB;
  gemm_k<2,2,1,4,true><<<gm32, blk, 0, stream>>>(
      x, Wh, Wl, b_in, hbuf, M, 128);

  for (int i = 0; i < 3; ++i) {
    const size_t wlin_off = (size_t)(1 + i) * 16384;
    const size_t w1_off   = (size_t)(4 + i) * 16384;
    const size_t w2_off   = (size_t)(7 + i) * 16384;
    // h2 = h @ W_lin[i] + b_lin[i]   (h read fully; then dead)
    gemm_k<2,2,1,4,false><<<gm32, blk, 0, stream>>>(
        hbuf, Wh + wlin_off, Wl + wlin_off, b_lin + i * 128, h2buf, M, 128);
    // hs = packed-bf16 top-32 rows  -> reuse dead h buffer
    unsigned int* hs = (unsigned int*)hbuf;
    maxk_k<<<(M + 3) / 4, blk, 0, stream>>>(h2buf, hs, M);
    // neigh = segment_sum(hs[src], dst)
    gather_k<<<(M + 3) / 4, blk, 0, stream>>>(hs, offs, eidx, neigh, M);
    // h = relu(((1+eps)h2+neigh)@W1+b1) @ W2 + b2   (fused, hs dead) -> hbuf
    fusedgemm_k<<<gm32, blk, 0, stream>>>(
        h2buf, neigh, eps + i, Wh + w1_off, Wl + w1_off, b1 + i * 128,
        Wh + w2_off, Wl + w2_off, b2 + i * 128, hbuf, M);
  }

  // out = h @ W_out + b_out   (fp32, 40 cols)
  const size_t wo_off = (size_t)10 * 16384;
  gemm_k<4,1,1,3,false><<<(M + 63) / 64, blk, 0, stream>>>(
      hbuf, Wh + wo_off, Wl + wo_off, b_out, (float*)d_out, M, 40);
}

// Round 15
// 604.127 us; speedup vs baseline: 1.2102x; 1.2102x over previous
//
#include <hip/hip_runtime.h>

typedef __bf16 bf16x8 __attribute__((ext_vector_type(8)));
typedef float f32x4 __attribute__((ext_vector_type(4)));

__device__ inline unsigned short f2b(float f) {
  unsigned int u = __float_as_uint(f);
  u += 0x7fffu + ((u >> 16) & 1u);
  return (unsigned short)(u >> 16);
}
__device__ inline float b2f(unsigned short u) {
  return __uint_as_float(((unsigned int)u) << 16);
}

// XOR swizzle for [R][128] bf16 LDS tiles (element index)
__device__ inline int swz(int r, int c) { return r * 128 + (c ^ ((r & 7) << 3)); }

__device__ inline bf16x8 ldfrag(const unsigned short* p) {
  uint4 v = *(const uint4*)p;
  bf16x8 r;
  __builtin_memcpy(&r, &v, 16);
  return r;
}

// ------------- weight prep: fp32 [K][N] -> bf16 hi/lo [n][k], 11 slots 128x128 ----
__global__ __launch_bounds__(256) void prep_wt(
    const float* __restrict__ W_in, const float* __restrict__ W_lin,
    const float* __restrict__ W1, const float* __restrict__ W2,
    const float* __restrict__ W_out, unsigned short* __restrict__ Wh,
    unsigned short* __restrict__ Wl)
{
  int slot = blockIdx.y;
  int e = blockIdx.x * 256 + threadIdx.x;   // 0..16383
  int n = e >> 7, k = e & 127;
  const float* srcp; int N;
  if (slot == 0)      { srcp = W_in;                   N = 128; }
  else if (slot < 4)  { srcp = W_lin + (slot-1)*16384; N = 128; }
  else if (slot < 7)  { srcp = W1   + (slot-4)*16384;  N = 128; }
  else if (slot < 10) { srcp = W2   + (slot-7)*16384;  N = 128; }
  else                { srcp = W_out;                  N = 40;  }
  float v = (n < N) ? srcp[k * N + n] : 0.f;
  unsigned short hi = f2b(v);
  float lo = v - b2f(hi);
  Wh[slot * 16384 + e] = hi;
  Wl[slot * 16384 + e] = f2b(lo);
}

// ------------- plain GEMM: C = act(A[Mx128] @ W[128xNcols] + b), A fp32 ----------
// 3-term bf16 split emulation: A*W = Ah*Wh + Ah*Wl + Al*Wh  (error ~2^-17)
// R11 lesson: BM=32 doubled per-block weight-panel reads -> regression. Keep
// BM=64, raise waves/block to TPB/64 instead (same B traffic, 2x wave supply).
template<int TPB, int WM, int WN, int MF, int NF, bool RELU>
__global__ __launch_bounds__(TPB) void gemm_k(
    const float* __restrict__ Ap, const unsigned short* __restrict__ Wh,
    const unsigned short* __restrict__ Wl, const float* __restrict__ bias,
    float* __restrict__ Cp, int M, int Ncols)
{
  constexpr int BM = WM * MF * 16;
  static_assert(WM * WN * 64 == TPB, "wave count");
  static_assert(BM * 128 % (TPB * 4) == 0, "");
  __shared__ __align__(16) unsigned short ldsAh[BM * 128];
  __shared__ __align__(16) unsigned short ldsAl[BM * 128];

  const int tid = threadIdx.x;
  const int row0 = blockIdx.x * BM;

  constexpr int AIT = BM * 128 / (TPB * 4);
#pragma unroll
  for (int it = 0; it < AIT; ++it) {
    int flat = it * (TPB * 4) + tid * 4;
    int r = flat >> 7, c = flat & 127;
    int gr = row0 + r;
    float4 v = make_float4(0.f, 0.f, 0.f, 0.f);
    if (gr < M) v = *(const float4*)(Ap + (size_t)gr * 128 + c);
    ushort4 h4, l4;
    h4.x = f2b(v.x); l4.x = f2b(v.x - b2f(h4.x));
    h4.y = f2b(v.y); l4.y = f2b(v.y - b2f(h4.y));
    h4.z = f2b(v.z); l4.z = f2b(v.z - b2f(h4.z));
    h4.w = f2b(v.w); l4.w = f2b(v.w - b2f(h4.w));
    *(ushort4*)&ldsAh[swz(r, c)] = h4;
    *(ushort4*)&ldsAl[swz(r, c)] = l4;
  }
  __syncthreads();

  const int wid = tid >> 6, lane = tid & 63;
  const int wm = wid / WN, wn = wid % WN;
  const int l15 = lane & 15, lk = lane >> 4;

  f32x4 acc[MF][NF];
#pragma unroll
  for (int mi = 0; mi < MF; ++mi)
#pragma unroll
    for (int ni = 0; ni < NF; ++ni)
      acc[mi][ni] = (f32x4){0.f, 0.f, 0.f, 0.f};

  const unsigned short* wbh = Wh + (size_t)(wn * NF * 16 + l15) * 128;
  const unsigned short* wbl = Wl + (size_t)(wn * NF * 16 + l15) * 128;

#pragma unroll
  for (int kk = 0; kk < 4; ++kk) {
    const int kc = kk * 32 + lk * 8;
    bf16x8 ah[MF], al[MF];
#pragma unroll
    for (int mi = 0; mi < MF; ++mi) {
      int rr = wm * MF * 16 + mi * 16 + l15;
      ah[mi] = ldfrag(&ldsAh[swz(rr, kc)]);
      al[mi] = ldfrag(&ldsAl[swz(rr, kc)]);
    }
    bf16x8 bh[NF], bl[NF];
#pragma unroll
    for (int ni = 0; ni < NF; ++ni) {
      bh[ni] = ldfrag(wbh + ni * 16 * 128 + kc);
      bl[ni] = ldfrag(wbl + ni * 16 * 128 + kc);
    }
#pragma unroll
    for (int mi = 0; mi < MF; ++mi)
#pragma unroll
      for (int ni = 0; ni < NF; ++ni) {
        acc[mi][ni] = __builtin_amdgcn_mfma_f32_16x16x32_bf16(ah[mi], bl[ni], acc[mi][ni], 0, 0, 0);
        acc[mi][ni] = __builtin_amdgcn_mfma_f32_16x16x32_bf16(al[mi], bh[ni], acc[mi][ni], 0, 0, 0);
        acc[mi][ni] = __builtin_amdgcn_mfma_f32_16x16x32_bf16(ah[mi], bh[ni], acc[mi][ni], 0, 0, 0);
      }
  }

#pragma unroll
  for (int ni = 0; ni < NF; ++ni) {
    int col = wn * NF * 16 + ni * 16 + l15;
    if (col >= Ncols) continue;
    float bc = bias[col];
#pragma unroll
    for (int mi = 0; mi < MF; ++mi) {
      int rbase = row0 + wm * MF * 16 + mi * 16 + lk * 4;
#pragma unroll
      for (int j = 0; j < 4; ++j) {
        int r = rbase + j;
        if (r >= M) continue;
        float v = acc[mi][ni][j] + bc;
        if (RELU) v = fmaxf(v, 0.f);
        Cp[(size_t)r * Ncols + col] = v;
      }
    }
  }
}

// ------------- fused double GEMM: h = (relu(((1+eps)h2+neigh)@W1+b1)) @ W2 + b2 --
// BM=64, 8 waves (WM=2,WN=4,MF=2,NF=2). Full BN=128 required: phase 2 consumes
// complete t rows as its K dim. Phase1 acc -> t -> hi/lo bf16 into staging LDS.
__global__ __launch_bounds__(512) void fusedgemm_k(
    const float* __restrict__ h2, const float* __restrict__ neigh,
    const float* __restrict__ epsp,
    const unsigned short* __restrict__ Wh1, const unsigned short* __restrict__ Wl1,
    const float* __restrict__ b1,
    const unsigned short* __restrict__ Wh2, const unsigned short* __restrict__ Wl2,
    const float* __restrict__ b2, float* __restrict__ Hout, int M)
{
  constexpr int WM = 2, WN = 4, MF = 2, NF = 2;
  constexpr int BM = WM * MF * 16;   // 64
  __shared__ __align__(16) unsigned short ldsAh[BM * 128];
  __shared__ __align__(16) unsigned short ldsAl[BM * 128];

  const int tid = threadIdx.x;
  const int row0 = blockIdx.x * BM;
  const float epsf = 1.0f + epsp[0];

  // stage A = (1+eps)*h2 + neigh  (fp32 -> hi/lo, swizzled)
#pragma unroll
  for (int it = 0; it < BM * 128 / 2048; ++it) {
    int flat = it * 2048 + tid * 4;
    int r = flat >> 7, c = flat & 127;
    int gr = row0 + r;
    float4 v = make_float4(0.f, 0.f, 0.f, 0.f);
    if (gr < M) {
      v = *(const float4*)(h2 + (size_t)gr * 128 + c);
      float4 ng = *(const float4*)(neigh + (size_t)gr * 128 + c);
      v = make_float4(fmaf(epsf, v.x, ng.x), fmaf(epsf, v.y, ng.y),
                      fmaf(epsf, v.z, ng.z), fmaf(epsf, v.w, ng.w));
    }
    ushort4 h4, l4;
    h4.x = f2b(v.x); l4.x = f2b(v.x - b2f(h4.x));
    h4.y = f2b(v.y); l4.y = f2b(v.y - b2f(h4.y));
    h4.z = f2b(v.z); l4.z = f2b(v.z - b2f(h4.z));
    h4.w = f2b(v.w); l4.w = f2b(v.w - b2f(h4.w));
    *(ushort4*)&ldsAh[swz(r, c)] = h4;
    *(ushort4*)&ldsAl[swz(r, c)] = l4;
  }
  __syncthreads();

  const int wid = tid >> 6, lane = tid & 63;
  const int wm = wid / WN, wn = wid % WN;
  const int l15 = lane & 15, lk = lane >> 4;

  f32x4 acc[MF][NF];
#pragma unroll
  for (int mi = 0; mi < MF; ++mi)
#pragma unroll
    for (int ni = 0; ni < NF; ++ni)
      acc[mi][ni] = (f32x4){0.f, 0.f, 0.f, 0.f};

  // ---- phase 1: t = A @ W1 ----
  {
    const unsigned short* wbh = Wh1 + (size_t)(wn * NF * 16 + l15) * 128;
    const unsigned short* wbl = Wl1 + (size_t)(wn * NF * 16 + l15) * 128;
#pragma unroll
    for (int kk = 0; kk < 4; ++kk) {
      const int kc = kk * 32 + lk * 8;
      bf16x8 ah[MF], al[MF];
#pragma unroll
      for (int mi = 0; mi < MF; ++mi) {
        int rr = wm * MF * 16 + mi * 16 + l15;
        ah[mi] = ldfrag(&ldsAh[swz(rr, kc)]);
        al[mi] = ldfrag(&ldsAl[swz(rr, kc)]);
      }
      bf16x8 bh[NF], bl[NF];
#pragma unroll
      for (int ni = 0; ni < NF; ++ni) {
        bh[ni] = ldfrag(wbh + ni * 16 * 128 + kc);
        bl[ni] = ldfrag(wbl + ni * 16 * 128 + kc);
      }
#pragma unroll
      for (int mi = 0; mi < MF; ++mi)
#pragma unroll
        for (int ni = 0; ni < NF; ++ni) {
          acc[mi][ni] = __builtin_amdgcn_mfma_f32_16x16x32_bf16(ah[mi], bl[ni], acc[mi][ni], 0, 0, 0);
          acc[mi][ni] = __builtin_amdgcn_mfma_f32_16x16x32_bf16(al[mi], bh[ni], acc[mi][ni], 0, 0, 0);
          acc[mi][ni] = __builtin_amdgcn_mfma_f32_16x16x32_bf16(ah[mi], bh[ni], acc[mi][ni], 0, 0, 0);
        }
    }
  }
  __syncthreads();   // all phase-1 LDS reads done before t overwrites staging

  // t = relu(acc + b1) -> hi/lo bf16 into staging LDS (block-local rows/cols)
#pragma unroll
  for (int ni = 0; ni < NF; ++ni) {
    int c = wn * NF * 16 + ni * 16 + l15;
    float bc = b1[c];
#pragma unroll
    for (int mi = 0; mi < MF; ++mi) {
#pragma unroll
      for (int j = 0; j < 4; ++j) {
        int r = wm * MF * 16 + mi * 16 + lk * 4 + j;
        float v = fmaxf(acc[mi][ni][j] + bc, 0.f);
        unsigned short hi = f2b(v);
        ldsAh[swz(r, c)] = hi;
        ldsAl[swz(r, c)] = f2b(v - b2f(hi));
        acc[mi][ni][j] = 0.f;   // reset for phase 2
      }
    }
  }
  __syncthreads();   // t complete before phase-2 reads

  // ---- phase 2: h = t @ W2 ----
  {
    const unsigned short* wbh = Wh2 + (size_t)(wn * NF * 16 + l15) * 128;
    const unsigned short* wbl = Wl2 + (size_t)(wn * NF * 16 + l15) * 128;
#pragma unroll
    for (int kk = 0; kk < 4; ++kk) {
      const int kc = kk * 32 + lk * 8;
      bf16x8 ah[MF], al[MF];
#pragma unroll
      for (int mi = 0; mi < MF; ++mi) {
        int rr = wm * MF * 16 + mi * 16 + l15;
        ah[mi] = ldfrag(&ldsAh[swz(rr, kc)]);
        al[mi] = ldfrag(&ldsAl[swz(rr, kc)]);
      }
      bf16x8 bh[NF], bl[NF];
#pragma unroll
      for (int ni = 0; ni < NF; ++ni) {
        bh[ni] = ldfrag(wbh + ni * 16 * 128 + kc);
        bl[ni] = ldfrag(wbl + ni * 16 * 128 + kc);
      }
#pragma unroll
      for (int mi = 0; mi < MF; ++mi)
#pragma unroll
        for (int ni = 0; ni < NF; ++ni) {
          acc[mi][ni] = __builtin_amdgcn_mfma_f32_16x16x32_bf16(ah[mi], bl[ni], acc[mi][ni], 0, 0, 0);
          acc[mi][ni] = __builtin_amdgcn_mfma_f32_16x16x32_bf16(al[mi], bh[ni], acc[mi][ni], 0, 0, 0);
          acc[mi][ni] = __builtin_amdgcn_mfma_f32_16x16x32_bf16(ah[mi], bh[ni], acc[mi][ni], 0, 0, 0);
        }
    }
  }

#pragma unroll
  for (int ni = 0; ni < NF; ++ni) {
    int col = wn * NF * 16 + ni * 16 + l15;
    float bc = b2[col];
#pragma unroll
    for (int mi = 0; mi < MF; ++mi) {
#pragma unroll
      for (int j = 0; j < 4; ++j) {
        int r = row0 + wm * MF * 16 + mi * 16 + lk * 4 + j;
        if (r >= M) continue;
        Hout[(size_t)r * 128 + col] = acc[mi][ni][j] + bc;
      }
    }
  }
}

// ------------- maxk: exact fp32 top-32 select; write packed bf16 dense rows ------
__global__ __launch_bounds__(256) void maxk_k(const float* __restrict__ h,
                                              unsigned int* __restrict__ hs, int M)
{
  int row = blockIdx.x * 4 + (threadIdx.x >> 6);
  if (row >= M) return;
  int lane = threadIdx.x & 63;
  float2 pr = *(const float2*)(h + (size_t)row * 128 + lane * 2);
  auto key = [](float f) -> unsigned int {
    unsigned int b = __float_as_uint(f);
    return (b & 0x80000000u) ? ~b : (b | 0x80000000u);
  };
  unsigned int k0 = key(pr.x), k1 = key(pr.y);
  unsigned int thr = 0;
#pragma unroll
  for (int b = 31; b >= 0; --b) {
    unsigned int t = thr | (1u << b);
    int c = __popcll(__ballot(k0 >= t)) + __popcll(__ballot(k1 >= t));
    if (c >= 32) thr = t;   // uniform across wave
  }
  unsigned long long g0 = __ballot(k0 > thr), g1 = __ballot(k1 > thr);
  unsigned long long e0 = __ballot(k0 == thr), e1 = __ballot(k1 == thr);
  int cgt = __popcll(g0) + __popcll(g1);
  unsigned long long mlt = (1ull << lane) - 1ull;
  unsigned long long mle = mlt | (1ull << lane);
  bool keep0 = (k0 > thr) ||
               ((k0 == thr) && (cgt + __popcll(e0 & mlt) + __popcll(e1 & mlt)) < 32);
  bool keep1 = (k1 > thr) ||
               ((k1 == thr) && (cgt + __popcll(e0 & mle) + __popcll(e1 & mlt)) < 32);
  unsigned int w0 = keep0 ? (unsigned int)f2b(pr.x) : 0u;
  unsigned int w1 = keep1 ? (unsigned int)f2b(pr.y) : 0u;
  hs[(size_t)row * 64 + lane] = w0 | (w1 << 16);
}

// ------------- CSR build (once per call; graph reused across 3 layers) -----------
__global__ __launch_bounds__(256) void hist_k(const int* __restrict__ dst,
                                              int* __restrict__ cnt, int E)
{
  int e = blockIdx.x * 256 + threadIdx.x;
  if (e < E) atomicAdd(&cnt[dst[e]], 1);
}

__global__ __launch_bounds__(256) void bsum_k(const int* __restrict__ cnt,
                                              int* __restrict__ bsum, int M)
{
  __shared__ int s[256];
  int i = blockIdx.x * 256 + threadIdx.x;
  int t = threadIdx.x;
  s[t] = (i < M) ? cnt[i] : 0;
  __syncthreads();
  for (int st = 128; st > 0; st >>= 1) {
    if (t < st) s[t] += s[t + st];
    __syncthreads();
  }
  if (t == 0) bsum[blockIdx.x] = s[0];
}

__global__ __launch_bounds__(1024) void scanb_k(int* __restrict__ bsum, int NB)
{
  __shared__ int s[1024];
  int t = threadIdx.x;
  int v = (t < NB) ? bsum[t] : 0;
  s[t] = v;
  __syncthreads();
  for (int st = 1; st < 1024; st <<= 1) {
    int a = (t >= st) ? s[t - st] : 0;
    __syncthreads();
    s[t] += a;
    __syncthreads();
  }
  if (t < NB) bsum[t] = s[t] - v;   // exclusive
}

__global__ __launch_bounds__(256) void scano_k(const int* __restrict__ cnt,
                                               const int* __restrict__ bsum,
                                               int* __restrict__ offs,
                                               int* __restrict__ cur, int M, int E)
{
  __shared__ int s[256];
  int i = blockIdx.x * 256 + threadIdx.x;
  int t = threadIdx.x;
  int v = (i < M) ? cnt[i] : 0;
  s[t] = v;
  __syncthreads();
  for (int st = 1; st < 256; st <<= 1) {
    int a = (t >= st) ? s[t - st] : 0;
    __syncthreads();
    s[t] += a;
    __syncthreads();
  }
  int excl = s[t] - v + bsum[blockIdx.x];
  if (i < M) { offs[i] = excl; cur[i] = excl; }
  if (blockIdx.x == 0 && t == 0) offs[M] = E;
}

__global__ __launch_bounds__(256) void fill_k(const int* __restrict__ src,
                                              const int* __restrict__ dst,
                                              int* __restrict__ cur,
                                              unsigned short* __restrict__ eidx, int E)
{
  int e = blockIdx.x * 256 + threadIdx.x;
  if (e >= E) return;
  int d = dst[e];
  int p = atomicAdd(&cur[d], 1);
  eidx[p] = (unsigned short)src[e];
}

// ------------- gather: neigh[d] = sum of bf16 hs rows over in-edges --------------
__global__ __launch_bounds__(256) void gather_k(
    const unsigned int* __restrict__ hs, const int* __restrict__ offs,
    const unsigned short* __restrict__ eidx, float* __restrict__ neigh, int M)
{
  const int w = threadIdx.x >> 6, lane = threadIdx.x & 63;
  const int d = blockIdx.x * 4 + w;
  if (d >= M) return;
  const int start = offs[d], end = offs[d + 1];
  float ax = 0.f, ay = 0.f;
  int i = start;
  for (; i + 4 <= end; i += 4) {
    int s0 = eidx[i], s1 = eidx[i + 1], s2 = eidx[i + 2], s3 = eidx[i + 3];
    unsigned int u0 = hs[(size_t)s0 * 64 + lane];
    unsigned int u1 = hs[(size_t)s1 * 64 + lane];
    unsigned int u2 = hs[(size_t)s2 * 64 + lane];
    unsigned int u3 = hs[(size_t)s3 * 64 + lane];
    ax += (b2f(u0 & 0xffffu) + b2f(u1 & 0xffffu)) +
          (b2f(u2 & 0xffffu) + b2f(u3 & 0xffffu));
    ay += (b2f(u0 >> 16) + b2f(u1 >> 16)) + (b2f(u2 >> 16) + b2f(u3 >> 16));
  }
  for (; i < end; ++i) {
    unsigned int u0 = hs[(size_t)eidx[i] * 64 + lane];
    ax += b2f(u0 & 0xffffu);
    ay += b2f(u0 >> 16);
  }
  float2 o;
  o.x = ax;
  o.y = ay;
  *(float2*)(neigh + (size_t)d * 128 + (size_t)lane * 2) = o;
}

extern "C" void kernel_launch(void* const* d_in, const int* in_sizes, int n_in,
                              void* d_out, int out_size, void* d_ws, size_t ws_size,
                              hipStream_t stream)
{
  const float* x     = (const float*)d_in[0];
  const int*   src   = (const int*)d_in[1];
  const int*   dst   = (const int*)d_in[2];
  const float* W_in  = (const float*)d_in[3];
  const float* b_in  = (const float*)d_in[4];
  const float* W_lin = (const float*)d_in[5];
  const float* b_lin = (const float*)d_in[6];
  const float* W1    = (const float*)d_in[7];
  const float* b1    = (const float*)d_in[8];
  const float* W2    = (const float*)d_in[9];
  const float* b2    = (const float*)d_in[10];
  const float* eps   = (const float*)d_in[11];
  const float* W_out = (const float*)d_in[12];
  const float* b_out = (const float*)d_in[13];

  const int M = in_sizes[0] / 128;   // 50000
  const int E = in_sizes[1];         // 800000

  const int NB = (M + 255) / 256;
  char* ws = (char*)d_ws;
  unsigned short* Wh = (unsigned short*)ws;
  size_t off = (size_t)11 * 16384 * 2;
  unsigned short* Wl = (unsigned short*)(ws + off); off += (size_t)11 * 16384 * 2;
  float* PA    = (float*)(ws + off); off += (size_t)M * 128 * 4;
  float* PB    = (float*)(ws + off); off += (size_t)M * 128 * 4;
  float* neigh = (float*)(ws + off); off += (size_t)M * 128 * 4;
  int* offs = (int*)(ws + off); off += (size_t)(M + 1) * 4;
  unsigned short* eidx = (unsigned short*)(ws + off); off += (size_t)E * 2;
  int* cnt  = (int*)(ws + off); off += (size_t)M * 4;
  int* cur  = (int*)(ws + off); off += (size_t)M * 4;
  int* bsum = (int*)(ws + off); off += (size_t)NB * 4;

  dim3 blk(256);
  dim3 blk512(512);
  prep_wt<<<dim3(64, 11), blk, 0, stream>>>(W_in, W_lin, W1, W2, W_out, Wh, Wl);

  // ---- CSR build (graph constant across layers) ----
  (void)hipMemsetAsync(cnt, 0, (size_t)M * 4, stream);
  hist_k<<<(E + 255) / 256, blk, 0, stream>>>(dst, cnt, E);
  bsum_k<<<NB, blk, 0, stream>>>(cnt, bsum, M);
  scanb_k<<<1, 1024, 0, stream>>>(bsum, NB);
  scano_k<<<NB, blk, 0, stream>>>(cnt, bsum, offs, cur, M, E);
  fill_k<<<(E + 255) / 256, blk, 0, stream>>>(src, dst, cur, eidx, E);

  const int gm64 = (M + 63) / 64;   // BM=64 tiles, 8-wave blocks

  // h = relu(x @ W_in + b_in) -> PA   (h lives in PA for the whole net)
  float* hbuf = PA;
  float* h2buf = PB;
  gemm_k<512,2,4,2,2,true><<<gm64, blk512, 0, stream>>>(
      x, Wh, Wl, b_in, hbuf, M, 128);

  for (int i = 0; i < 3; ++i) {
    const size_t wlin_off = (size_t)(1 + i) * 16384;
    const size_t w1_off   = (size_t)(4 + i) * 16384;
    const size_t w2_off   = (size_t)(7 + i) * 16384;
    // h2 = h @ W_lin[i] + b_lin[i]   (h read fully; then dead)
    gemm_k<512,2,4,2,2,false><<<gm64, blk512, 0, stream>>>(
        hbuf, Wh + wlin_off, Wl + wlin_off, b_lin + i * 128, h2buf, M, 128);
    // hs = packed-bf16 top-32 rows  -> reuse dead h buffer
    unsigned int* hs = (unsigned int*)hbuf;
    maxk_k<<<(M + 3) / 4, blk, 0, stream>>>(h2buf, hs, M);
    // neigh = segment_sum(hs[src], dst)
    gather_k<<<(M + 3) / 4, blk, 0, stream>>>(hs, offs, eidx, neigh, M);
    // h = relu(((1+eps)h2+neigh)@W1+b1) @ W2 + b2   (fused, hs dead) -> hbuf
    fusedgemm_k<<<gm64, blk512, 0, stream>>>(
        h2buf, neigh, eps + i, Wh + w1_off, Wl + w1_off, b1 + i * 128,
        Wh + w2_off, Wl + w2_off, b2 + i * 128, hbuf, M);
  }

  // out = h @ W_out + b_out   (fp32, 40 cols)
  const size_t wo_off = (size_t)10 * 16384;
  gemm_k<256,4,1,1,3,false><<<gm64, blk, 0, stream>>>(
      hbuf, Wh + wo_off, Wl + wo_off, b_out, (float*)d_out, M, 40);
}

// Round 16
// 590.184 us; speedup vs baseline: 1.2388x; 1.0236x over previous
//
#include <hip/hip_runtime.h>

typedef __bf16 bf16x8 __attribute__((ext_vector_type(8)));
typedef float f32x4 __attribute__((ext_vector_type(4)));

__device__ inline unsigned short f2b(float f) {
  unsigned int u = __float_as_uint(f);
  u += 0x7fffu + ((u >> 16) & 1u);
  return (unsigned short)(u >> 16);
}
__device__ inline float b2f(unsigned short u) {
  return __uint_as_float(((unsigned int)u) << 16);
}

// XOR swizzle for [R][128] bf16 LDS tiles (element index)
__device__ inline int swz(int r, int c) { return r * 128 + (c ^ ((r & 7) << 3)); }

__device__ inline bf16x8 ldfrag(const unsigned short* p) {
  uint4 v = *(const uint4*)p;
  bf16x8 r;
  __builtin_memcpy(&r, &v, 16);
  return r;
}

// ------------- weight prep: fp32 [K][N] -> bf16 hi/lo [n][k], 11 slots 128x128 ----
__global__ __launch_bounds__(256) void prep_wt(
    const float* __restrict__ W_in, const float* __restrict__ W_lin,
    const float* __restrict__ W1, const float* __restrict__ W2,
    const float* __restrict__ W_out, unsigned short* __restrict__ Wh,
    unsigned short* __restrict__ Wl)
{
  int slot = blockIdx.y;
  int e = blockIdx.x * 256 + threadIdx.x;   // 0..16383
  int n = e >> 7, k = e & 127;
  const float* srcp; int N;
  if (slot == 0)      { srcp = W_in;                   N = 128; }
  else if (slot < 4)  { srcp = W_lin + (slot-1)*16384; N = 128; }
  else if (slot < 7)  { srcp = W1   + (slot-4)*16384;  N = 128; }
  else if (slot < 10) { srcp = W2   + (slot-7)*16384;  N = 128; }
  else                { srcp = W_out;                  N = 40;  }
  float v = (n < N) ? srcp[k * N + n] : 0.f;
  unsigned short hi = f2b(v);
  float lo = v - b2f(hi);
  Wh[slot * 16384 + e] = hi;
  Wl[slot * 16384 + e] = f2b(lo);
}

// ------------- plain GEMM: C = act(A[Mx128] @ W[128xNcols] + b), A fp32 ----------
// 3-term bf16 split: A*W = Ah*Wh + Ah*Wl + Al*Wh (error ~2^-17). BM=64, 8 waves.
// MAXK: fuse exact-fp32 top-32 select into epilogue via LDS tile overlay; write
// packed-bf16 hs rows at 512B stride (hs aliases the dead A-input buffer; the
// 512B stride keeps each block's hs writes inside its OWN staged rows -> no race).
template<int TPB, int WM, int WN, int MF, int NF, bool RELU, bool MAXK>
__global__ __launch_bounds__(TPB) void gemm_k(
    const float* __restrict__ Ap, const unsigned short* __restrict__ Wh,
    const unsigned short* __restrict__ Wl, const float* __restrict__ bias,
    float* __restrict__ Cp, int M, int Ncols, unsigned int* __restrict__ hs)
{
  constexpr int BM = WM * MF * 16;
  static_assert(WM * WN * 64 == TPB, "wave count");
  static_assert(BM * 128 % (TPB * 4) == 0, "");
  // single buffer: hi-plane [0, BM*128), lo-plane [BM*128, 2*BM*128) ushorts.
  // After MFMA, overlaid as BM*128 fp32 output tile (same 4*BM*128 bytes).
  __shared__ __align__(16) unsigned short ldsBuf[BM * 128 * 2];
  unsigned short* ldsAh = ldsBuf;
  unsigned short* ldsAl = ldsBuf + BM * 128;

  const int tid = threadIdx.x;
  const int row0 = blockIdx.x * BM;

  constexpr int AIT = BM * 128 / (TPB * 4);
#pragma unroll
  for (int it = 0; it < AIT; ++it) {
    int flat = it * (TPB * 4) + tid * 4;
    int r = flat >> 7, c = flat & 127;
    int gr = row0 + r;
    float4 v = make_float4(0.f, 0.f, 0.f, 0.f);
    if (gr < M) v = *(const float4*)(Ap + (size_t)gr * 128 + c);
    ushort4 h4, l4;
    h4.x = f2b(v.x); l4.x = f2b(v.x - b2f(h4.x));
    h4.y = f2b(v.y); l4.y = f2b(v.y - b2f(h4.y));
    h4.z = f2b(v.z); l4.z = f2b(v.z - b2f(h4.z));
    h4.w = f2b(v.w); l4.w = f2b(v.w - b2f(h4.w));
    *(ushort4*)&ldsAh[swz(r, c)] = h4;
    *(ushort4*)&ldsAl[swz(r, c)] = l4;
  }
  __syncthreads();

  const int wid = tid >> 6, lane = tid & 63;
  const int wm = wid / WN, wn = wid % WN;
  const int l15 = lane & 15, lk = lane >> 4;

  f32x4 acc[MF][NF];
#pragma unroll
  for (int mi = 0; mi < MF; ++mi)
#pragma unroll
    for (int ni = 0; ni < NF; ++ni)
      acc[mi][ni] = (f32x4){0.f, 0.f, 0.f, 0.f};

  const unsigned short* wbh = Wh + (size_t)(wn * NF * 16 + l15) * 128;
  const unsigned short* wbl = Wl + (size_t)(wn * NF * 16 + l15) * 128;

#pragma unroll
  for (int kk = 0; kk < 4; ++kk) {
    const int kc = kk * 32 + lk * 8;
    bf16x8 ah[MF], al[MF];
#pragma unroll
    for (int mi = 0; mi < MF; ++mi) {
      int rr = wm * MF * 16 + mi * 16 + l15;
      ah[mi] = ldfrag(&ldsAh[swz(rr, kc)]);
      al[mi] = ldfrag(&ldsAl[swz(rr, kc)]);
    }
    bf16x8 bh[NF], bl[NF];
#pragma unroll
    for (int ni = 0; ni < NF; ++ni) {
      bh[ni] = ldfrag(wbh + ni * 16 * 128 + kc);
      bl[ni] = ldfrag(wbl + ni * 16 * 128 + kc);
    }
#pragma unroll
    for (int mi = 0; mi < MF; ++mi)
#pragma unroll
      for (int ni = 0; ni < NF; ++ni) {
        acc[mi][ni] = __builtin_amdgcn_mfma_f32_16x16x32_bf16(ah[mi], bl[ni], acc[mi][ni], 0, 0, 0);
        acc[mi][ni] = __builtin_amdgcn_mfma_f32_16x16x32_bf16(al[mi], bh[ni], acc[mi][ni], 0, 0, 0);
        acc[mi][ni] = __builtin_amdgcn_mfma_f32_16x16x32_bf16(ah[mi], bh[ni], acc[mi][ni], 0, 0, 0);
      }
  }

  if constexpr (MAXK) __syncthreads();   // all waves done reading staging LDS
  float* tile = (float*)ldsBuf;          // overlay: BM*128 fp32 = same 32KB

#pragma unroll
  for (int ni = 0; ni < NF; ++ni) {
    int col = wn * NF * 16 + ni * 16 + l15;
    if (col >= Ncols) continue;
    float bc = bias[col];
#pragma unroll
    for (int mi = 0; mi < MF; ++mi) {
      int lr = wm * MF * 16 + mi * 16 + lk * 4;
#pragma unroll
      for (int j = 0; j < 4; ++j) {
        int r = row0 + lr + j;
        float v = acc[mi][ni][j] + bc;
        if (RELU) v = fmaxf(v, 0.f);
        if constexpr (MAXK) tile[(lr + j) * 128 + col] = v;
        if (r < M) Cp[(size_t)r * Ncols + col] = v;
      }
    }
  }

  if constexpr (MAXK) {
    __syncthreads();   // tile complete
    constexpr int NW = TPB / 64;
    constexpr int ROWS = BM / NW;   // rows per wave
#pragma unroll
    for (int rr = 0; rr < ROWS; ++rr) {
      int lrow = wid * ROWS + rr;
      int grow = row0 + lrow;
      if (grow >= M) break;   // uniform across wave
      float2 pr = *(const float2*)&tile[lrow * 128 + lane * 2];
      auto key = [](float f) -> unsigned int {
        unsigned int b = __float_as_uint(f);
        return (b & 0x80000000u) ? ~b : (b | 0x80000000u);
      };
      unsigned int k0 = key(pr.x), k1 = key(pr.y);
      unsigned int thr = 0;
#pragma unroll
      for (int b = 31; b >= 0; --b) {
        unsigned int t = thr | (1u << b);
        int c = __popcll(__ballot(k0 >= t)) + __popcll(__ballot(k1 >= t));
        if (c >= 32) thr = t;
      }
      unsigned long long g0 = __ballot(k0 > thr), g1 = __ballot(k1 > thr);
      unsigned long long e0 = __ballot(k0 == thr), e1 = __ballot(k1 == thr);
      int cgt = __popcll(g0) + __popcll(g1);
      unsigned long long mlt = (1ull << lane) - 1ull;
      unsigned long long mle = mlt | (1ull << lane);
      bool keep0 = (k0 > thr) ||
                   ((k0 == thr) && (cgt + __popcll(e0 & mlt) + __popcll(e1 & mlt)) < 32);
      bool keep1 = (k1 > thr) ||
                   ((k1 == thr) && (cgt + __popcll(e0 & mle) + __popcll(e1 & mlt)) < 32);
      unsigned int w0 = keep0 ? (unsigned int)f2b(pr.x) : 0u;
      unsigned int w1 = keep1 ? (unsigned int)f2b(pr.y) : 0u;
      hs[(size_t)grow * 128 + lane] = w0 | (w1 << 16);   // 512B-stride rows
    }
  }
}

// ------------- fused double GEMM: h = (relu(((1+eps)h2+neigh)@W1+b1)) @ W2 + b2 --
// BM=64, 8 waves (WM=2,WN=4,MF=2,NF=2). Full BN=128 required: phase 2 consumes
// complete t rows as its K dim. Phase1 acc -> t -> hi/lo bf16 into staging LDS.
__global__ __launch_bounds__(512) void fusedgemm_k(
    const float* __restrict__ h2, const float* __restrict__ neigh,
    const float* __restrict__ epsp,
    const unsigned short* __restrict__ Wh1, const unsigned short* __restrict__ Wl1,
    const float* __restrict__ b1,
    const unsigned short* __restrict__ Wh2, const unsigned short* __restrict__ Wl2,
    const float* __restrict__ b2, float* __restrict__ Hout, int M)
{
  constexpr int WM = 2, WN = 4, MF = 2, NF = 2;
  constexpr int BM = WM * MF * 16;   // 64
  __shared__ __align__(16) unsigned short ldsAh[BM * 128];
  __shared__ __align__(16) unsigned short ldsAl[BM * 128];

  const int tid = threadIdx.x;
  const int row0 = blockIdx.x * BM;
  const float epsf = 1.0f + epsp[0];

  // stage A = (1+eps)*h2 + neigh  (fp32 -> hi/lo, swizzled)
#pragma unroll
  for (int it = 0; it < BM * 128 / 2048; ++it) {
    int flat = it * 2048 + tid * 4;
    int r = flat >> 7, c = flat & 127;
    int gr = row0 + r;
    float4 v = make_float4(0.f, 0.f, 0.f, 0.f);
    if (gr < M) {
      v = *(const float4*)(h2 + (size_t)gr * 128 + c);
      float4 ng = *(const float4*)(neigh + (size_t)gr * 128 + c);
      v = make_float4(fmaf(epsf, v.x, ng.x), fmaf(epsf, v.y, ng.y),
                      fmaf(epsf, v.z, ng.z), fmaf(epsf, v.w, ng.w));
    }
    ushort4 h4, l4;
    h4.x = f2b(v.x); l4.x = f2b(v.x - b2f(h4.x));
    h4.y = f2b(v.y); l4.y = f2b(v.y - b2f(h4.y));
    h4.z = f2b(v.z); l4.z = f2b(v.z - b2f(h4.z));
    h4.w = f2b(v.w); l4.w = f2b(v.w - b2f(h4.w));
    *(ushort4*)&ldsAh[swz(r, c)] = h4;
    *(ushort4*)&ldsAl[swz(r, c)] = l4;
  }
  __syncthreads();

  const int wid = tid >> 6, lane = tid & 63;
  const int wm = wid / WN, wn = wid % WN;
  const int l15 = lane & 15, lk = lane >> 4;

  f32x4 acc[MF][NF];
#pragma unroll
  for (int mi = 0; mi < MF; ++mi)
#pragma unroll
    for (int ni = 0; ni < NF; ++ni)
      acc[mi][ni] = (f32x4){0.f, 0.f, 0.f, 0.f};

  // ---- phase 1: t = A @ W1 ----
  {
    const unsigned short* wbh = Wh1 + (size_t)(wn * NF * 16 + l15) * 128;
    const unsigned short* wbl = Wl1 + (size_t)(wn * NF * 16 + l15) * 128;
#pragma unroll
    for (int kk = 0; kk < 4; ++kk) {
      const int kc = kk * 32 + lk * 8;
      bf16x8 ah[MF], al[MF];
#pragma unroll
      for (int mi = 0; mi < MF; ++mi) {
        int rr = wm * MF * 16 + mi * 16 + l15;
        ah[mi] = ldfrag(&ldsAh[swz(rr, kc)]);
        al[mi] = ldfrag(&ldsAl[swz(rr, kc)]);
      }
      bf16x8 bh[NF], bl[NF];
#pragma unroll
      for (int ni = 0; ni < NF; ++ni) {
        bh[ni] = ldfrag(wbh + ni * 16 * 128 + kc);
        bl[ni] = ldfrag(wbl + ni * 16 * 128 + kc);
      }
#pragma unroll
      for (int mi = 0; mi < MF; ++mi)
#pragma unroll
        for (int ni = 0; ni < NF; ++ni) {
          acc[mi][ni] = __builtin_amdgcn_mfma_f32_16x16x32_bf16(ah[mi], bl[ni], acc[mi][ni], 0, 0, 0);
          acc[mi][ni] = __builtin_amdgcn_mfma_f32_16x16x32_bf16(al[mi], bh[ni], acc[mi][ni], 0, 0, 0);
          acc[mi][ni] = __builtin_amdgcn_mfma_f32_16x16x32_bf16(ah[mi], bh[ni], acc[mi][ni], 0, 0, 0);
        }
    }
  }
  __syncthreads();   // all phase-1 LDS reads done before t overwrites staging

  // t = relu(acc + b1) -> hi/lo bf16 into staging LDS (block-local rows/cols)
#pragma unroll
  for (int ni = 0; ni < NF; ++ni) {
    int c = wn * NF * 16 + ni * 16 + l15;
    float bc = b1[c];
#pragma unroll
    for (int mi = 0; mi < MF; ++mi) {
#pragma unroll
      for (int j = 0; j < 4; ++j) {
        int r = wm * MF * 16 + mi * 16 + lk * 4 + j;
        float v = fmaxf(acc[mi][ni][j] + bc, 0.f);
        unsigned short hi = f2b(v);
        ldsAh[swz(r, c)] = hi;
        ldsAl[swz(r, c)] = f2b(v - b2f(hi));
        acc[mi][ni][j] = 0.f;   // reset for phase 2
      }
    }
  }
  __syncthreads();   // t complete before phase-2 reads

  // ---- phase 2: h = t @ W2 ----
  {
    const unsigned short* wbh = Wh2 + (size_t)(wn * NF * 16 + l15) * 128;
    const unsigned short* wbl = Wl2 + (size_t)(wn * NF * 16 + l15) * 128;
#pragma unroll
    for (int kk = 0; kk < 4; ++kk) {
      const int kc = kk * 32 + lk * 8;
      bf16x8 ah[MF], al[MF];
#pragma unroll
      for (int mi = 0; mi < MF; ++mi) {
        int rr = wm * MF * 16 + mi * 16 + l15;
        ah[mi] = ldfrag(&ldsAh[swz(rr, kc)]);
        al[mi] = ldfrag(&ldsAl[swz(rr, kc)]);
      }
      bf16x8 bh[NF], bl[NF];
#pragma unroll
      for (int ni = 0; ni < NF; ++ni) {
        bh[ni] = ldfrag(wbh + ni * 16 * 128 + kc);
        bl[ni] = ldfrag(wbl + ni * 16 * 128 + kc);
      }
#pragma unroll
      for (int mi = 0; mi < MF; ++mi)
#pragma unroll
        for (int ni = 0; ni < NF; ++ni) {
          acc[mi][ni] = __builtin_amdgcn_mfma_f32_16x16x32_bf16(ah[mi], bl[ni], acc[mi][ni], 0, 0, 0);
          acc[mi][ni] = __builtin_amdgcn_mfma_f32_16x16x32_bf16(al[mi], bh[ni], acc[mi][ni], 0, 0, 0);
          acc[mi][ni] = __builtin_amdgcn_mfma_f32_16x16x32_bf16(ah[mi], bh[ni], acc[mi][ni], 0, 0, 0);
        }
    }
  }

#pragma unroll
  for (int ni = 0; ni < NF; ++ni) {
    int col = wn * NF * 16 + ni * 16 + l15;
    float bc = b2[col];
#pragma unroll
    for (int mi = 0; mi < MF; ++mi) {
#pragma unroll
      for (int j = 0; j < 4; ++j) {
        int r = row0 + wm * MF * 16 + mi * 16 + lk * 4 + j;
        if (r >= M) continue;
        Hout[(size_t)r * 128 + col] = acc[mi][ni][j] + bc;
      }
    }
  }
}

// ------------- CSR build (once per call; graph reused across 3 layers) -----------
__global__ __launch_bounds__(256) void hist_k(const int* __restrict__ dst,
                                              int* __restrict__ cnt, int E)
{
  int e = blockIdx.x * 256 + threadIdx.x;
  if (e < E) atomicAdd(&cnt[dst[e]], 1);
}

__global__ __launch_bounds__(256) void bsum_k(const int* __restrict__ cnt,
                                              int* __restrict__ bsum, int M)
{
  __shared__ int s[256];
  int i = blockIdx.x * 256 + threadIdx.x;
  int t = threadIdx.x;
  s[t] = (i < M) ? cnt[i] : 0;
  __syncthreads();
  for (int st = 128; st > 0; st >>= 1) {
    if (t < st) s[t] += s[t + st];
    __syncthreads();
  }
  if (t == 0) bsum[blockIdx.x] = s[0];
}

__global__ __launch_bounds__(1024) void scanb_k(int* __restrict__ bsum, int NB)
{
  __shared__ int s[1024];
  int t = threadIdx.x;
  int v = (t < NB) ? bsum[t] : 0;
  s[t] = v;
  __syncthreads();
  for (int st = 1; st < 1024; st <<= 1) {
    int a = (t >= st) ? s[t - st] : 0;
    __syncthreads();
    s[t] += a;
    __syncthreads();
  }
  if (t < NB) bsum[t] = s[t] - v;   // exclusive
}

__global__ __launch_bounds__(256) void scano_k(const int* __restrict__ cnt,
                                               const int* __restrict__ bsum,
                                               int* __restrict__ offs,
                                               int* __restrict__ cur, int M, int E)
{
  __shared__ int s[256];
  int i = blockIdx.x * 256 + threadIdx.x;
  int t = threadIdx.x;
  int v = (i < M) ? cnt[i] : 0;
  s[t] = v;
  __syncthreads();
  for (int st = 1; st < 256; st <<= 1) {
    int a = (t >= st) ? s[t - st] : 0;
    __syncthreads();
    s[t] += a;
    __syncthreads();
  }
  int excl = s[t] - v + bsum[blockIdx.x];
  if (i < M) { offs[i] = excl; cur[i] = excl; }
  if (blockIdx.x == 0 && t == 0) offs[M] = E;
}

__global__ __launch_bounds__(256) void fill_k(const int* __restrict__ src,
                                              const int* __restrict__ dst,
                                              int* __restrict__ cur,
                                              unsigned short* __restrict__ eidx, int E)
{
  int e = blockIdx.x * 256 + threadIdx.x;
  if (e >= E) return;
  int d = dst[e];
  int p = atomicAdd(&cur[d], 1);
  eidx[p] = (unsigned short)src[e];
}

// ------------- gather: neigh[d] = sum of bf16 hs rows (512B stride) over edges ---
// Unroll x8: avg degree 16 -> 8 independent 256B row-reads in flight.
__global__ __launch_bounds__(256) void gather_k(
    const unsigned int* __restrict__ hs, const int* __restrict__ offs,
    const unsigned short* __restrict__ eidx, float* __restrict__ neigh, int M)
{
  const int w = threadIdx.x >> 6, lane = threadIdx.x & 63;
  const int d = blockIdx.x * 4 + w;
  if (d >= M) return;
  const int start = offs[d], end = offs[d + 1];
  float ax = 0.f, ay = 0.f;
  int i = start;
  for (; i + 8 <= end; i += 8) {
    unsigned int u0 = hs[(size_t)eidx[i]     * 128 + lane];
    unsigned int u1 = hs[(size_t)eidx[i + 1] * 128 + lane];
    unsigned int u2 = hs[(size_t)eidx[i + 2] * 128 + lane];
    unsigned int u3 = hs[(size_t)eidx[i + 3] * 128 + lane];
    unsigned int u4 = hs[(size_t)eidx[i + 4] * 128 + lane];
    unsigned int u5 = hs[(size_t)eidx[i + 5] * 128 + lane];
    unsigned int u6 = hs[(size_t)eidx[i + 6] * 128 + lane];
    unsigned int u7 = hs[(size_t)eidx[i + 7] * 128 + lane];
    ax += ((b2f(u0 & 0xffffu) + b2f(u1 & 0xffffu)) + (b2f(u2 & 0xffffu) + b2f(u3 & 0xffffu))) +
          ((b2f(u4 & 0xffffu) + b2f(u5 & 0xffffu)) + (b2f(u6 & 0xffffu) + b2f(u7 & 0xffffu)));
    ay += ((b2f(u0 >> 16) + b2f(u1 >> 16)) + (b2f(u2 >> 16) + b2f(u3 >> 16))) +
          ((b2f(u4 >> 16) + b2f(u5 >> 16)) + (b2f(u6 >> 16) + b2f(u7 >> 16)));
  }
  for (; i + 4 <= end; i += 4) {
    unsigned int u0 = hs[(size_t)eidx[i]     * 128 + lane];
    unsigned int u1 = hs[(size_t)eidx[i + 1] * 128 + lane];
    unsigned int u2 = hs[(size_t)eidx[i + 2] * 128 + lane];
    unsigned int u3 = hs[(size_t)eidx[i + 3] * 128 + lane];
    ax += (b2f(u0 & 0xffffu) + b2f(u1 & 0xffffu)) + (b2f(u2 & 0xffffu) + b2f(u3 & 0xffffu));
    ay += (b2f(u0 >> 16) + b2f(u1 >> 16)) + (b2f(u2 >> 16) + b2f(u3 >> 16));
  }
  for (; i < end; ++i) {
    unsigned int u0 = hs[(size_t)eidx[i] * 128 + lane];
    ax += b2f(u0 & 0xffffu);
    ay += b2f(u0 >> 16);
  }
  float2 o;
  o.x = ax;
  o.y = ay;
  *(float2*)(neigh + (size_t)d * 128 + (size_t)lane * 2) = o;
}

extern "C" void kernel_launch(void* const* d_in, const int* in_sizes, int n_in,
                              void* d_out, int out_size, void* d_ws, size_t ws_size,
                              hipStream_t stream)
{
  const float* x     = (const float*)d_in[0];
  const int*   src   = (const int*)d_in[1];
  const int*   dst   = (const int*)d_in[2];
  const float* W_in  = (const float*)d_in[3];
  const float* b_in  = (const float*)d_in[4];
  const float* W_lin = (const float*)d_in[5];
  const float* b_lin = (const float*)d_in[6];
  const float* W1    = (const float*)d_in[7];
  const float* b1    = (const float*)d_in[8];
  const float* W2    = (const float*)d_in[9];
  const float* b2    = (const float*)d_in[10];
  const float* eps   = (const float*)d_in[11];
  const float* W_out = (const float*)d_in[12];
  const float* b_out = (const float*)d_in[13];

  const int M = in_sizes[0] / 128;   // 50000
  const int E = in_sizes[1];         // 800000

  const int NB = (M + 255) / 256;
  char* ws = (char*)d_ws;
  unsigned short* Wh = (unsigned short*)ws;
  size_t off = (size_t)11 * 16384 * 2;
  unsigned short* Wl = (unsigned short*)(ws + off); off += (size_t)11 * 16384 * 2;
  float* PA    = (float*)(ws + off); off += (size_t)M * 128 * 4;
  float* PB    = (float*)(ws + off); off += (size_t)M * 128 * 4;
  float* neigh = (float*)(ws + off); off += (size_t)M * 128 * 4;
  int* offs = (int*)(ws + off); off += (size_t)(M + 1) * 4;
  unsigned short* eidx = (unsigned short*)(ws + off); off += (size_t)E * 2;
  int* cnt  = (int*)(ws + off); off += (size_t)M * 4;
  int* cur  = (int*)(ws + off); off += (size_t)M * 4;
  int* bsum = (int*)(ws + off); off += (size_t)NB * 4;

  dim3 blk(256);
  dim3 blk512(512);
  prep_wt<<<dim3(64, 11), blk, 0, stream>>>(W_in, W_lin, W1, W2, W_out, Wh, Wl);

  // ---- CSR build (graph constant across layers) ----
  (void)hipMemsetAsync(cnt, 0, (size_t)M * 4, stream);
  hist_k<<<(E + 255) / 256, blk, 0, stream>>>(dst, cnt, E);
  bsum_k<<<NB, blk, 0, stream>>>(cnt, bsum, M);
  scanb_k<<<1, 1024, 0, stream>>>(bsum, NB);
  scano_k<<<NB, blk, 0, stream>>>(cnt, bsum, offs, cur, M, E);
  fill_k<<<(E + 255) / 256, blk, 0, stream>>>(src, dst, cur, eidx, E);

  const int gm64 = (M + 63) / 64;   // BM=64 tiles, 8-wave blocks

  // h = relu(x @ W_in + b_in) -> PA   (h lives in PA for the whole net)
  float* hbuf = PA;
  float* h2buf = PB;
  gemm_k<512,2,4,2,2,true,false><<<gm64, blk512, 0, stream>>>(
      x, Wh, Wl, b_in, hbuf, M, 128, nullptr);

  for (int i = 0; i < 3; ++i) {
    const size_t wlin_off = (size_t)(1 + i) * 16384;
    const size_t w1_off   = (size_t)(4 + i) * 16384;
    const size_t w2_off   = (size_t)(7 + i) * 16384;
    // h2 = h @ W_lin[i] + b_lin[i], AND hs = top-32(h2) fused into epilogue.
    // hs aliases hbuf at 512B row stride: block reads its own h rows (staged
    // first), then writes hs only into those same rows' slots -> race-free.
    unsigned int* hs = (unsigned int*)hbuf;
    gemm_k<512,2,4,2,2,false,true><<<gm64, blk512, 0, stream>>>(
        hbuf, Wh + wlin_off, Wl + wlin_off, b_lin + i * 128, h2buf, M, 128, hs);
    // neigh = segment_sum(hs[src], dst)
    gather_k<<<(M + 3) / 4, blk, 0, stream>>>(hs, offs, eidx, neigh, M);
    // h = relu(((1+eps)h2+neigh)@W1+b1) @ W2 + b2   (fused, hs dead) -> hbuf
    fusedgemm_k<<<gm64, blk512, 0, stream>>>(
        h2buf, neigh, eps + i, Wh + w1_off, Wl + w1_off, b1 + i * 128,
        Wh + w2_off, Wl + w2_off, b2 + i * 128, hbuf, M);
  }

  // out = h @ W_out + b_out   (fp32, 40 cols)
  const size_t wo_off = (size_t)10 * 16384;
  gemm_k<256,4,1,1,3,false,false><<<gm64, blk, 0, stream>>>(
      hbuf, Wh + wo_off, Wl + wo_off, b_out, (float*)d_out, M, 40, nullptr);
}